// Round 6
// baseline (634.979 us; speedup 1.0000x reference)
//
#include <hip/hip_runtime.h>

#define NN 100000
#define EE 1600000
#define C 256
#define OUTC 10
#define NG 64

#define SB 1024
#define NB ((NN + SB - 1) / SB)

// agg_pool decomposition: 4 waves/block, each wave owns NODES_PER_GROUP nodes
#define NODES_PER_GROUP 8
#define NODES_PER_BLOCK 32      // 4 waves * 8 nodes; 100000 = 32 * 3125 exactly

typedef __bf16 bf16x8 __attribute__((ext_vector_type(8)));
typedef float f32x4 __attribute__((ext_vector_type(4)));

// ---------------- bf16 helpers (RNE) ----------------
__device__ __forceinline__ ushort f2bf(float f) {
    unsigned u = __float_as_uint(f);
    return (ushort)((u + 0x7fffu + ((u >> 16) & 1u)) >> 16);
}
__device__ __forceinline__ bf16x8 as_bf16x8(uint4 v) {
    union { uint4 u; bf16x8 b; } c; c.u = v; return c.b;
}

// ---------------- degree histogram (in-degree, real edges, x4 vectorized) ----------------
__global__ void degree_kernel(const int* __restrict__ ei, int* __restrict__ indeg) {
    int e4 = blockIdx.x * blockDim.x + threadIdx.x;
    if (e4 < EE / 4) {
        int4 d = *(const int4*)(ei + EE + (size_t)e4 * 4);
        atomicAdd(&indeg[d.x], 1);
        atomicAdd(&indeg[d.y], 1);
        atomicAdd(&indeg[d.z], 1);
        atomicAdd(&indeg[d.w], 1);
    }
}

// ---------------- per-graph node counts: LDS histogram ----------------
__global__ __launch_bounds__(1024) void count_kernel(const int* __restrict__ batch,
                                                     float* __restrict__ cnt) {
    __shared__ int h[NG];
    if (threadIdx.x < NG) h[threadIdx.x] = 0;
    __syncthreads();
    int i = blockIdx.x * blockDim.x + threadIdx.x;
    if (i < NN) atomicAdd(&h[batch[i]], 1);
    __syncthreads();
    if (threadIdx.x < NG) {
        int v = h[threadIdx.x];
        if (v > 0) atomicAdd(&cnt[threadIdx.x], (float)v);
    }
}

// ---------------- hierarchical exclusive scan of indeg -> rowstart ----------------
__global__ __launch_bounds__(256) void partial_sum_kernel(const int* __restrict__ indeg,
                                                          int* __restrict__ bsum) {
    __shared__ int red[256];
    const int b = blockIdx.x;
    const int t = threadIdx.x;
    int base = b * SB + t * 4;
    int s = 0;
    #pragma unroll
    for (int j = 0; j < 4; j++) {
        int i = base + j;
        if (i < NN) s += indeg[i];
    }
    red[t] = s;
    __syncthreads();
    for (int off = 128; off > 0; off >>= 1) {
        if (t < off) red[t] += red[t + off];
        __syncthreads();
    }
    if (t == 0) bsum[b] = red[0];
}

__global__ void scan_partials_kernel(const int* __restrict__ bsum, int* __restrict__ boff) {
    __shared__ int lds[NB];
    int t = threadIdx.x;
    if (t < NB) lds[t] = bsum[t];
    __syncthreads();
    if (t == 0) {
        int acc = 0;
        for (int i = 0; i < NB; i++) { int v = lds[i]; lds[i] = acc; acc += v; }
    }
    __syncthreads();
    if (t < NB) boff[t] = lds[t];
}

// scatter_scan: writes exclusive-scan rowstart AND dinv (fused)
__global__ __launch_bounds__(256) void scatter_scan_kernel(const int* __restrict__ indeg,
                                                           const int* __restrict__ boff,
                                                           int* __restrict__ rowstart,
                                                           float* __restrict__ dinv) {
    __shared__ int lds[256];
    const int b = blockIdx.x;
    const int t = threadIdx.x;
    int base = b * SB + t * 4;
    int v[4];
    int s = 0;
    #pragma unroll
    for (int j = 0; j < 4; j++) {
        int i = base + j;
        v[j] = (i < NN) ? indeg[i] : 0;
        s += v[j];
    }
    lds[t] = s;
    __syncthreads();
    for (int off = 1; off < 256; off <<= 1) {
        int tmp = (t >= off) ? lds[t - off] : 0;
        __syncthreads();
        lds[t] += tmp;
        __syncthreads();
    }
    int excl = lds[t] - s + boff[b];
    #pragma unroll
    for (int j = 0; j < 4; j++) {
        int i = base + j;
        if (i < NN) {
            rowstart[i] = excl;
            dinv[i] = rsqrtf((float)v[j] + 1.0f);
        }
        excl += v[j];
    }
}

// ---------------- CSR fill: bumps rowstart in place; afterwards rowstart[i] = row-end ----------------
__global__ void fill_kernel(const int* __restrict__ ei, int* __restrict__ rowstart,
                            int* __restrict__ csrcol) {
    int e = blockIdx.x * blockDim.x + threadIdx.x;
    if (e < EE) {
        int s = ei[e];
        int d = ei[EE + e];
        int p = atomicAdd(&rowstart[d], 1);
        csrcol[p] = s;
    }
}

// ---------------- W1 -> bf16 fragment-order pack ----------------
__global__ __launch_bounds__(256) void w1pack_kernel(const float* __restrict__ W1,
                                                     ushort* __restrict__ w1f) {
    int t = blockIdx.x * 256 + threadIdx.x;   // 0..65535 = k*256 + n
    int k = t >> 8, n = t & 255;
    int kb = k >> 5, q = (k >> 3) & 3, j = k & 7;
    int nt = n >> 4, ln = (n & 15) + q * 16;
    w1f[(size_t)(((kb * 16 + nt) * 64) + ln) * 8 + j] = f2bf(W1[t]);
}

// ---------------- g = bf16((x @ W1) * dinv[row]) — MFMA, LDS-free ----------------
__global__ __launch_bounds__(256) void gemm_mfma_kernel(const float* __restrict__ x,
                                                        const ushort* __restrict__ w1f,
                                                        const float* __restrict__ dinv,
                                                        ushort* __restrict__ g) {
    const int lane = threadIdx.x & 63;
    const int wid = threadIdx.x >> 6;
    const int wave = blockIdx.x * 4 + wid;
    const int r0 = wave * 32;
    if (r0 >= NN) return;
    const int mrow = lane & 15;
    const int q = lane >> 4;

    f32x4 acc[2][16];
    #pragma unroll
    for (int mt = 0; mt < 2; mt++)
        #pragma unroll
        for (int nt = 0; nt < 16; nt++)
            acc[mt][nt] = (f32x4){0.f, 0.f, 0.f, 0.f};

    const float* xp0 = x + (size_t)(r0 + mrow) * C + q * 8;
    const float* xp1 = xp0 + (size_t)16 * C;
    const ushort* bp = w1f + (size_t)lane * 8;

    #pragma unroll 1
    for (int kb = 0; kb < 8; kb++) {
        const int ko = kb * 32;
        float4 a0lo = *(const float4*)(xp0 + ko);
        float4 a0hi = *(const float4*)(xp0 + ko + 4);
        float4 a1lo = *(const float4*)(xp1 + ko);
        float4 a1hi = *(const float4*)(xp1 + ko + 4);
        bf16x8 a0, a1;
        a0[0] = (__bf16)a0lo.x; a0[1] = (__bf16)a0lo.y;
        a0[2] = (__bf16)a0lo.z; a0[3] = (__bf16)a0lo.w;
        a0[4] = (__bf16)a0hi.x; a0[5] = (__bf16)a0hi.y;
        a0[6] = (__bf16)a0hi.z; a0[7] = (__bf16)a0hi.w;
        a1[0] = (__bf16)a1lo.x; a1[1] = (__bf16)a1lo.y;
        a1[2] = (__bf16)a1lo.z; a1[3] = (__bf16)a1lo.w;
        a1[4] = (__bf16)a1hi.x; a1[5] = (__bf16)a1hi.y;
        a1[6] = (__bf16)a1hi.z; a1[7] = (__bf16)a1hi.w;

        const ushort* bkb = bp + (size_t)kb * 16 * 512;
        #pragma unroll
        for (int nt = 0; nt < 16; nt++) {
            bf16x8 b = as_bf16x8(*(const uint4*)(bkb + (size_t)nt * 512));
            acc[0][nt] = __builtin_amdgcn_mfma_f32_16x16x32_bf16(a0, b, acc[0][nt], 0, 0, 0);
            acc[1][nt] = __builtin_amdgcn_mfma_f32_16x16x32_bf16(a1, b, acc[1][nt], 0, 0, 0);
        }
    }

    #pragma unroll
    for (int mt = 0; mt < 2; mt++) {
        #pragma unroll
        for (int r = 0; r < 4; r++) {
            int row = r0 + mt * 16 + q * 4 + r;
            float dv = dinv[row];
            ushort* gp = g + (size_t)row * C + mrow;
            #pragma unroll
            for (int nt = 0; nt < 16; nt++)
                gp[nt * 16] = f2bf(acc[mt][nt][r] * dv);
        }
    }
}

// ---------------- aggregate + relu + fused mean-pool (paired-row gather) ----------------
// Lane layout: 8 ch x 2B = 16B/lane; half-wave 0 (lanes 0-31) covers one full
// 512B row, half-wave 1 a second row -> one dwordx4 wave-load = 2 rows (1KB).
// Unroll 8 virtual rows/iter = 4 paired loads in flight. Virtual row 0 = self.
__device__ __forceinline__ void acc_row(float s[8], uint4 v) {
    s[0] += __uint_as_float(v.x << 16);
    s[1] += __uint_as_float(v.x & 0xffff0000u);
    s[2] += __uint_as_float(v.y << 16);
    s[3] += __uint_as_float(v.y & 0xffff0000u);
    s[4] += __uint_as_float(v.z << 16);
    s[5] += __uint_as_float(v.z & 0xffff0000u);
    s[6] += __uint_as_float(v.w << 16);
    s[7] += __uint_as_float(v.w & 0xffff0000u);
}

__global__ __launch_bounds__(256) void agg_pool_kernel(const ushort* __restrict__ g,
                                                       const int* __restrict__ rowend,
                                                       const int* __restrict__ csrcol,
                                                       const float* __restrict__ dinv,
                                                       const float* __restrict__ b1,
                                                       const int* __restrict__ batch,
                                                       float* __restrict__ sums) {
    const int lane = threadIdx.x & 63;
    const int h = lane >> 5;
    const int cl = lane & 31;
    const int c8 = cl * 8;
    const int wid = threadIdx.x >> 6;
    const int nodeA = blockIdx.x * NODES_PER_BLOCK + wid * NODES_PER_GROUP;

    float bv[8];
    *(float4*)&bv[0] = *(const float4*)&b1[c8];
    *(float4*)&bv[4] = *(const float4*)&b1[c8 + 4];

    float pool[8] = {0.f, 0.f, 0.f, 0.f, 0.f, 0.f, 0.f, 0.f};
    int curb = -1;
    int rprev = (nodeA == 0) ? 0 : rowend[nodeA - 1];

    #pragma unroll 1
    for (int i = nodeA; i < nodeA + NODES_PER_GROUP; i++) {
        int r1 = rowend[i];
        int r0 = rprev;
        rprev = r1;
        int bi = batch[i];
        if (bi != curb) {
            if (curb >= 0 && h == 0) {
                #pragma unroll
                for (int t = 0; t < 8; t++)
                    atomicAdd(&sums[curb * C + c8 + t], pool[t]);
            }
            curb = bi;
            #pragma unroll
            for (int t = 0; t < 8; t++) pool[t] = 0.f;
        }
        const int cnt = 1 + (r1 - r0);      // virtual rows: self + edges
        float s[8] = {0.f, 0.f, 0.f, 0.f, 0.f, 0.f, 0.f, 0.f};

        #pragma unroll 1
        for (int j = 0; j < cnt; j += 8) {
            int vi[8];
            #pragma unroll
            for (int t = 0; t < 8; t++) {
                int jj = j + t;
                int idx = i;
                if (jj > 0 && jj < cnt) idx = csrcol[r0 + jj - 1];
                vi[t] = idx;
            }
            #pragma unroll
            for (int p = 0; p < 4; p++) {
                int jj = j + 2 * p + h;
                int row = h ? vi[2 * p + 1] : vi[2 * p];
                uint4 v = *(const uint4*)(g + (size_t)row * C + c8);
                if (jj < cnt) acc_row(s, v);
            }
        }
        // merge the two half-wave partial sums
        #pragma unroll
        for (int t = 0; t < 8; t++) s[t] += __shfl_xor(s[t], 32);
        float dv = dinv[i];
        #pragma unroll
        for (int t = 0; t < 8; t++)
            pool[t] += fmaxf(fmaf(dv, s[t], bv[t]), 0.f);
    }
    if (curb >= 0 && h == 0) {
        #pragma unroll
        for (int t = 0; t < 8; t++)
            atomicAdd(&sums[curb * C + c8 + t], pool[t]);
    }
}

// ---------------- pooled = sums/cnt; out = pooled @ W2 + b2 ----------------
__global__ __launch_bounds__(256) void final_kernel(const float* __restrict__ sums,
                                                    const float* __restrict__ cnt,
                                                    const float* __restrict__ W2,
                                                    const float* __restrict__ b2,
                                                    float* __restrict__ out) {
    __shared__ float p[C];
    int gi = blockIdx.x;
    float cdiv = fmaxf(cnt[gi], 1.0f);
    p[threadIdx.x] = sums[gi * C + threadIdx.x] / cdiv;
    __syncthreads();
    if (threadIdx.x < OUTC) {
        float acc = b2[threadIdx.x];
        for (int k = 0; k < C; k++) acc += p[k] * W2[k * OUTC + threadIdx.x];
        out[gi * OUTC + threadIdx.x] = acc;
    }
}

extern "C" void kernel_launch(void* const* d_in, const int* in_sizes, int n_in,
                              void* d_out, int out_size, void* d_ws, size_t ws_size,
                              hipStream_t stream) {
    const float* x     = (const float*)d_in[0];
    const int*   ei    = (const int*)d_in[1];
    const int*   batch = (const int*)d_in[2];
    const float* W1    = (const float*)d_in[3];
    const float* b1    = (const float*)d_in[4];
    const float* W2    = (const float*)d_in[5];
    const float* b2    = (const float*)d_in[6];
    float* out = (float*)d_out;

    char* w = (char*)d_ws;
    size_t off = 0;
    auto carve = [&](size_t bytes) {
        void* p = w + off;
        off = (off + bytes + 255) & ~(size_t)255;
        return p;
    };
    ushort* g       = (ushort*)carve((size_t)NN * C * 2);
    int*   rowstart = (int*)  carve((size_t)NN * 4);      // becomes row-end after fill
    float* dinv     = (float*)carve((size_t)NN * 4);
    int*   csrcol   = (int*)  carve((size_t)EE * 4);
    int*   bsum     = (int*)  carve((size_t)NB * 4);
    int*   boff     = (int*)  carve((size_t)NB * 4);
    ushort* w1f     = (ushort*)carve((size_t)C * C * 2);
    // contiguous zero-init region:
    int*   indeg    = (int*)  carve((size_t)NN * 4);
    float* sums     = (float*)carve((size_t)NG * C * 4);
    float* cnt      = (float*)carve((size_t)NG * 4);
    size_t zero_bytes = (size_t)((char*)cnt + (size_t)NG * 4 - (char*)indeg);

    hipMemsetAsync(indeg, 0, zero_bytes, stream);

    degree_kernel<<<(EE / 4 + 255) / 256, 256, 0, stream>>>(ei, indeg);
    count_kernel<<<(NN + 1023) / 1024, 1024, 0, stream>>>(batch, cnt);
    partial_sum_kernel<<<NB, 256, 0, stream>>>(indeg, bsum);
    scan_partials_kernel<<<1, 128, 0, stream>>>(bsum, boff);
    scatter_scan_kernel<<<NB, 256, 0, stream>>>(indeg, boff, rowstart, dinv);
    fill_kernel<<<(EE + 255) / 256, 256, 0, stream>>>(ei, rowstart, csrcol);
    w1pack_kernel<<<C * C / 256, 256, 0, stream>>>(W1, w1f);
    gemm_mfma_kernel<<<(NN / 32 + 3) / 4, 256, 0, stream>>>(x, w1f, dinv, g);
    agg_pool_kernel<<<NN / NODES_PER_BLOCK, 256, 0, stream>>>(
        g, rowstart, csrcol, dinv, b1, batch, sums);
    final_kernel<<<NG, 256, 0, stream>>>(sums, cnt, W2, b2, out);
}

// Round 7
// 522.610 us; speedup vs baseline: 1.2150x; 1.2150x over previous
//
#include <hip/hip_runtime.h>

#define NN 100000
#define EE 1600000
#define C 256
#define OUTC 10
#define NG 64

#define SB 1024
#define NB ((NN + SB - 1) / SB)

// agg_pool decomposition: 4 waves/block, each wave owns NODES_PER_GROUP nodes
#define NODES_PER_GROUP 8
#define NODES_PER_BLOCK 32      // 4 waves * 8 nodes; 100000 = 32 * 3125 exactly

typedef __bf16 bf16x8 __attribute__((ext_vector_type(8)));
typedef float f32x4 __attribute__((ext_vector_type(4)));
typedef float f32x2 __attribute__((ext_vector_type(2)));

// ---------------- bf16 helpers (RNE) ----------------
__device__ __forceinline__ ushort f2bf(float f) {
    unsigned u = __float_as_uint(f);
    return (ushort)((u + 0x7fffu + ((u >> 16) & 1u)) >> 16);
}
__device__ __forceinline__ bf16x8 as_bf16x8(uint4 v) {
    union { uint4 u; bf16x8 b; } c; c.u = v; return c.b;
}

// fp8 e4m3 encode/decode via HW converts (roundtrip-consistent on gfx950)
__device__ __forceinline__ uchar f2fp8(float f) {
    return (uchar)(__builtin_amdgcn_cvt_pk_fp8_f32(f, 0.f, 0, false) & 0xff);
}
__device__ __forceinline__ void acc_fp8x4(float4& s, unsigned v) {
    f32x2 lo = __builtin_amdgcn_cvt_pk_f32_fp8(v, false);
    f32x2 hi = __builtin_amdgcn_cvt_pk_f32_fp8(v, true);
    s.x += lo[0]; s.y += lo[1]; s.z += hi[0]; s.w += hi[1];
}

// ---------------- degree histogram (in-degree, real edges, x4 vectorized) ----------------
__global__ void degree_kernel(const int* __restrict__ ei, int* __restrict__ indeg) {
    int e4 = blockIdx.x * blockDim.x + threadIdx.x;
    if (e4 < EE / 4) {
        int4 d = *(const int4*)(ei + EE + (size_t)e4 * 4);
        atomicAdd(&indeg[d.x], 1);
        atomicAdd(&indeg[d.y], 1);
        atomicAdd(&indeg[d.z], 1);
        atomicAdd(&indeg[d.w], 1);
    }
}

// ---------------- per-graph node counts: LDS histogram ----------------
__global__ __launch_bounds__(1024) void count_kernel(const int* __restrict__ batch,
                                                     float* __restrict__ cnt) {
    __shared__ int h[NG];
    if (threadIdx.x < NG) h[threadIdx.x] = 0;
    __syncthreads();
    int i = blockIdx.x * blockDim.x + threadIdx.x;
    if (i < NN) atomicAdd(&h[batch[i]], 1);
    __syncthreads();
    if (threadIdx.x < NG) {
        int v = h[threadIdx.x];
        if (v > 0) atomicAdd(&cnt[threadIdx.x], (float)v);
    }
}

// ---------------- hierarchical exclusive scan of indeg -> rowstart ----------------
__global__ __launch_bounds__(256) void partial_sum_kernel(const int* __restrict__ indeg,
                                                          int* __restrict__ bsum) {
    __shared__ int red[256];
    const int b = blockIdx.x;
    const int t = threadIdx.x;
    int base = b * SB + t * 4;
    int s = 0;
    #pragma unroll
    for (int j = 0; j < 4; j++) {
        int i = base + j;
        if (i < NN) s += indeg[i];
    }
    red[t] = s;
    __syncthreads();
    for (int off = 128; off > 0; off >>= 1) {
        if (t < off) red[t] += red[t + off];
        __syncthreads();
    }
    if (t == 0) bsum[b] = red[0];
}

__global__ void scan_partials_kernel(const int* __restrict__ bsum, int* __restrict__ boff) {
    __shared__ int lds[NB];
    int t = threadIdx.x;
    if (t < NB) lds[t] = bsum[t];
    __syncthreads();
    if (t == 0) {
        int acc = 0;
        for (int i = 0; i < NB; i++) { int v = lds[i]; lds[i] = acc; acc += v; }
    }
    __syncthreads();
    if (t < NB) boff[t] = lds[t];
}

// scatter_scan: writes exclusive-scan rowstart AND dinv (fused)
__global__ __launch_bounds__(256) void scatter_scan_kernel(const int* __restrict__ indeg,
                                                           const int* __restrict__ boff,
                                                           int* __restrict__ rowstart,
                                                           float* __restrict__ dinv) {
    __shared__ int lds[256];
    const int b = blockIdx.x;
    const int t = threadIdx.x;
    int base = b * SB + t * 4;
    int v[4];
    int s = 0;
    #pragma unroll
    for (int j = 0; j < 4; j++) {
        int i = base + j;
        v[j] = (i < NN) ? indeg[i] : 0;
        s += v[j];
    }
    lds[t] = s;
    __syncthreads();
    for (int off = 1; off < 256; off <<= 1) {
        int tmp = (t >= off) ? lds[t - off] : 0;
        __syncthreads();
        lds[t] += tmp;
        __syncthreads();
    }
    int excl = lds[t] - s + boff[b];
    #pragma unroll
    for (int j = 0; j < 4; j++) {
        int i = base + j;
        if (i < NN) {
            rowstart[i] = excl;
            dinv[i] = rsqrtf((float)v[j] + 1.0f);
        }
        excl += v[j];
    }
}

// ---------------- CSR fill: bumps rowstart in place; afterwards rowstart[i] = row-end ----------------
__global__ void fill_kernel(const int* __restrict__ ei, int* __restrict__ rowstart,
                            int* __restrict__ csrcol) {
    int e = blockIdx.x * blockDim.x + threadIdx.x;
    if (e < EE) {
        int s = ei[e];
        int d = ei[EE + e];
        int p = atomicAdd(&rowstart[d], 1);
        csrcol[p] = s;
    }
}

// ---------------- W1 -> bf16 fragment-order pack ----------------
__global__ __launch_bounds__(256) void w1pack_kernel(const float* __restrict__ W1,
                                                     ushort* __restrict__ w1f) {
    int t = blockIdx.x * 256 + threadIdx.x;   // 0..65535 = k*256 + n
    int k = t >> 8, n = t & 255;
    int kb = k >> 5, q = (k >> 3) & 3, j = k & 7;
    int nt = n >> 4, ln = (n & 15) + q * 16;
    w1f[(size_t)(((kb * 16 + nt) * 64) + ln) * 8 + j] = f2bf(W1[t]);
}

// ---------------- g = fp8((x @ W1) * dinv[row]) — MFMA, LDS-free ----------------
__global__ __launch_bounds__(256) void gemm_mfma_kernel(const float* __restrict__ x,
                                                        const ushort* __restrict__ w1f,
                                                        const float* __restrict__ dinv,
                                                        uchar* __restrict__ g) {
    const int lane = threadIdx.x & 63;
    const int wid = threadIdx.x >> 6;
    const int wave = blockIdx.x * 4 + wid;
    const int r0 = wave * 32;
    if (r0 >= NN) return;
    const int mrow = lane & 15;
    const int q = lane >> 4;

    f32x4 acc[2][16];
    #pragma unroll
    for (int mt = 0; mt < 2; mt++)
        #pragma unroll
        for (int nt = 0; nt < 16; nt++)
            acc[mt][nt] = (f32x4){0.f, 0.f, 0.f, 0.f};

    const float* xp0 = x + (size_t)(r0 + mrow) * C + q * 8;
    const float* xp1 = xp0 + (size_t)16 * C;
    const ushort* bp = w1f + (size_t)lane * 8;

    #pragma unroll 1
    for (int kb = 0; kb < 8; kb++) {
        const int ko = kb * 32;
        float4 a0lo = *(const float4*)(xp0 + ko);
        float4 a0hi = *(const float4*)(xp0 + ko + 4);
        float4 a1lo = *(const float4*)(xp1 + ko);
        float4 a1hi = *(const float4*)(xp1 + ko + 4);
        bf16x8 a0, a1;
        a0[0] = (__bf16)a0lo.x; a0[1] = (__bf16)a0lo.y;
        a0[2] = (__bf16)a0lo.z; a0[3] = (__bf16)a0lo.w;
        a0[4] = (__bf16)a0hi.x; a0[5] = (__bf16)a0hi.y;
        a0[6] = (__bf16)a0hi.z; a0[7] = (__bf16)a0hi.w;
        a1[0] = (__bf16)a1lo.x; a1[1] = (__bf16)a1lo.y;
        a1[2] = (__bf16)a1lo.z; a1[3] = (__bf16)a1lo.w;
        a1[4] = (__bf16)a1hi.x; a1[5] = (__bf16)a1hi.y;
        a1[6] = (__bf16)a1hi.z; a1[7] = (__bf16)a1hi.w;

        const ushort* bkb = bp + (size_t)kb * 16 * 512;
        #pragma unroll
        for (int nt = 0; nt < 16; nt++) {
            bf16x8 b = as_bf16x8(*(const uint4*)(bkb + (size_t)nt * 512));
            acc[0][nt] = __builtin_amdgcn_mfma_f32_16x16x32_bf16(a0, b, acc[0][nt], 0, 0, 0);
            acc[1][nt] = __builtin_amdgcn_mfma_f32_16x16x32_bf16(a1, b, acc[1][nt], 0, 0, 0);
        }
    }

    #pragma unroll
    for (int mt = 0; mt < 2; mt++) {
        #pragma unroll
        for (int r = 0; r < 4; r++) {
            int row = r0 + mt * 16 + q * 4 + r;
            float dv = dinv[row];
            uchar* gp = g + (size_t)row * C + mrow;
            #pragma unroll
            for (int nt = 0; nt < 16; nt++)
                gp[nt * 16] = f2fp8(acc[mt][nt][r] * dv);
        }
    }
}

// ---------------- aggregate + relu + fused mean-pool (fp8 gather, unroll 8) ----------------
// Lane = 4 contiguous channels (4B fp8); 64 lanes cover a 256B row per load.
// 8 independent row-gathers in flight per wave. fp32 accumulate. No LDS, no shuffles.
__global__ __launch_bounds__(256) void agg_pool_kernel(const unsigned* __restrict__ g32,
                                                       const int* __restrict__ rowend,
                                                       const int* __restrict__ csrcol,
                                                       const float* __restrict__ dinv,
                                                       const float* __restrict__ b1,
                                                       const int* __restrict__ batch,
                                                       float* __restrict__ sums) {
    const int lane = threadIdx.x & 63;
    const int wid = threadIdx.x >> 6;
    const int c4 = lane * 4;
    const int nodeA = blockIdx.x * NODES_PER_BLOCK + wid * NODES_PER_GROUP;
    const float4 bv = *(const float4*)&b1[c4];

    float4 pool = make_float4(0.f, 0.f, 0.f, 0.f);
    int curb = -1;
    int rprev = (nodeA == 0) ? 0 : rowend[nodeA - 1];

    #pragma unroll 1
    for (int i = nodeA; i < nodeA + NODES_PER_GROUP; i++) {
        int r1 = rowend[i];
        int r0 = rprev;
        rprev = r1;
        int bi = batch[i];
        if (bi != curb) {
            if (curb >= 0) {
                atomicAdd(&sums[curb * C + c4 + 0], pool.x);
                atomicAdd(&sums[curb * C + c4 + 1], pool.y);
                atomicAdd(&sums[curb * C + c4 + 2], pool.z);
                atomicAdd(&sums[curb * C + c4 + 3], pool.w);
            }
            curb = bi;
            pool = make_float4(0.f, 0.f, 0.f, 0.f);
        }
        float4 s = make_float4(0.f, 0.f, 0.f, 0.f);
        acc_fp8x4(s, g32[(size_t)i * 64 + lane]);     // self-loop term
        int e = r0;
        for (; e + 8 <= r1; e += 8) {
            int i0 = csrcol[e],     i1 = csrcol[e + 1];
            int i2 = csrcol[e + 2], i3 = csrcol[e + 3];
            int i4 = csrcol[e + 4], i5 = csrcol[e + 5];
            int i6 = csrcol[e + 6], i7 = csrcol[e + 7];
            unsigned v0 = g32[(size_t)i0 * 64 + lane];
            unsigned v1 = g32[(size_t)i1 * 64 + lane];
            unsigned v2 = g32[(size_t)i2 * 64 + lane];
            unsigned v3 = g32[(size_t)i3 * 64 + lane];
            unsigned v4 = g32[(size_t)i4 * 64 + lane];
            unsigned v5 = g32[(size_t)i5 * 64 + lane];
            unsigned v6 = g32[(size_t)i6 * 64 + lane];
            unsigned v7 = g32[(size_t)i7 * 64 + lane];
            acc_fp8x4(s, v0); acc_fp8x4(s, v1); acc_fp8x4(s, v2); acc_fp8x4(s, v3);
            acc_fp8x4(s, v4); acc_fp8x4(s, v5); acc_fp8x4(s, v6); acc_fp8x4(s, v7);
        }
        for (; e < r1; e++)
            acc_fp8x4(s, g32[(size_t)csrcol[e] * 64 + lane]);

        float dv = dinv[i];
        pool.x += fmaxf(fmaf(dv, s.x, bv.x), 0.f);
        pool.y += fmaxf(fmaf(dv, s.y, bv.y), 0.f);
        pool.z += fmaxf(fmaf(dv, s.z, bv.z), 0.f);
        pool.w += fmaxf(fmaf(dv, s.w, bv.w), 0.f);
    }
    if (curb >= 0) {
        atomicAdd(&sums[curb * C + c4 + 0], pool.x);
        atomicAdd(&sums[curb * C + c4 + 1], pool.y);
        atomicAdd(&sums[curb * C + c4 + 2], pool.z);
        atomicAdd(&sums[curb * C + c4 + 3], pool.w);
    }
}

// ---------------- pooled = sums/cnt; out = pooled @ W2 + b2 ----------------
__global__ __launch_bounds__(256) void final_kernel(const float* __restrict__ sums,
                                                    const float* __restrict__ cnt,
                                                    const float* __restrict__ W2,
                                                    const float* __restrict__ b2,
                                                    float* __restrict__ out) {
    __shared__ float p[C];
    int gi = blockIdx.x;
    float cdiv = fmaxf(cnt[gi], 1.0f);
    p[threadIdx.x] = sums[gi * C + threadIdx.x] / cdiv;
    __syncthreads();
    if (threadIdx.x < OUTC) {
        float acc = b2[threadIdx.x];
        for (int k = 0; k < C; k++) acc += p[k] * W2[k * OUTC + threadIdx.x];
        out[gi * OUTC + threadIdx.x] = acc;
    }
}

extern "C" void kernel_launch(void* const* d_in, const int* in_sizes, int n_in,
                              void* d_out, int out_size, void* d_ws, size_t ws_size,
                              hipStream_t stream) {
    const float* x     = (const float*)d_in[0];
    const int*   ei    = (const int*)d_in[1];
    const int*   batch = (const int*)d_in[2];
    const float* W1    = (const float*)d_in[3];
    const float* b1    = (const float*)d_in[4];
    const float* W2    = (const float*)d_in[5];
    const float* b2    = (const float*)d_in[6];
    float* out = (float*)d_out;

    char* w = (char*)d_ws;
    size_t off = 0;
    auto carve = [&](size_t bytes) {
        void* p = w + off;
        off = (off + bytes + 255) & ~(size_t)255;
        return p;
    };
    uchar* g        = (uchar*)carve((size_t)NN * C);      // fp8 e4m3
    int*   rowstart = (int*)  carve((size_t)NN * 4);      // becomes row-end after fill
    float* dinv     = (float*)carve((size_t)NN * 4);
    int*   csrcol   = (int*)  carve((size_t)EE * 4);
    int*   bsum     = (int*)  carve((size_t)NB * 4);
    int*   boff     = (int*)  carve((size_t)NB * 4);
    ushort* w1f     = (ushort*)carve((size_t)C * C * 2);
    // contiguous zero-init region:
    int*   indeg    = (int*)  carve((size_t)NN * 4);
    float* sums     = (float*)carve((size_t)NG * C * 4);
    float* cnt      = (float*)carve((size_t)NG * 4);
    size_t zero_bytes = (size_t)((char*)cnt + (size_t)NG * 4 - (char*)indeg);

    hipMemsetAsync(indeg, 0, zero_bytes, stream);

    degree_kernel<<<(EE / 4 + 255) / 256, 256, 0, stream>>>(ei, indeg);
    count_kernel<<<(NN + 1023) / 1024, 1024, 0, stream>>>(batch, cnt);
    partial_sum_kernel<<<NB, 256, 0, stream>>>(indeg, bsum);
    scan_partials_kernel<<<1, 128, 0, stream>>>(bsum, boff);
    scatter_scan_kernel<<<NB, 256, 0, stream>>>(indeg, boff, rowstart, dinv);
    fill_kernel<<<(EE + 255) / 256, 256, 0, stream>>>(ei, rowstart, csrcol);
    w1pack_kernel<<<C * C / 256, 256, 0, stream>>>(W1, w1f);
    gemm_mfma_kernel<<<(NN / 32 + 3) / 4, 256, 0, stream>>>(x, w1f, dinv, g);
    agg_pool_kernel<<<NN / NODES_PER_BLOCK, 256, 0, stream>>>(
        (const unsigned*)g, rowstart, csrcol, dinv, b1, batch, sums);
    final_kernel<<<NG, 256, 0, stream>>>(sums, cnt, W2, b2, out);
}

// Round 8
// 432.865 us; speedup vs baseline: 1.4669x; 1.2073x over previous
//
#include <hip/hip_runtime.h>

#define NN 100000
#define EE 1600000
#define C 256
#define OUTC 10
#define NG 64

#define NBK 391            // ceil(NN/256) dst-buckets of 256 nodes
#define CHUNK 16384        // edges per bucket_hist/scatter block
#define NBLK1 ((EE + CHUNK - 1) / CHUNK)

// agg_pool decomposition: 4 waves/block, each wave owns NODES_PER_GROUP nodes
#define NODES_PER_GROUP 8
#define NODES_PER_BLOCK 32      // 100000 = 32 * 3125 exactly

typedef __bf16 bf16x8 __attribute__((ext_vector_type(8)));
typedef float f32x4 __attribute__((ext_vector_type(4)));
typedef float f32x2 __attribute__((ext_vector_type(2)));

// ---------------- bf16 helpers (RNE) ----------------
__device__ __forceinline__ ushort f2bf(float f) {
    unsigned u = __float_as_uint(f);
    return (ushort)((u + 0x7fffu + ((u >> 16) & 1u)) >> 16);
}
__device__ __forceinline__ bf16x8 as_bf16x8(uint4 v) {
    union { uint4 u; bf16x8 b; } c; c.u = v; return c.b;
}

// fp8 e4m3 encode/decode via HW converts (roundtrip-consistent on gfx950)
__device__ __forceinline__ uchar f2fp8(float f) {
    return (uchar)(__builtin_amdgcn_cvt_pk_fp8_f32(f, 0.f, 0, false) & 0xff);
}
__device__ __forceinline__ void acc_fp8x4(float4& s, unsigned v) {
    f32x2 lo = __builtin_amdgcn_cvt_pk_f32_fp8(v, false);
    f32x2 hi = __builtin_amdgcn_cvt_pk_f32_fp8(v, true);
    s.x += lo[0]; s.y += lo[1]; s.z += hi[0]; s.w += hi[1];
}

// ---------------- per-graph node counts: LDS histogram ----------------
__global__ __launch_bounds__(1024) void count_kernel(const int* __restrict__ batch,
                                                     float* __restrict__ cnt) {
    __shared__ int h[NG];
    if (threadIdx.x < NG) h[threadIdx.x] = 0;
    __syncthreads();
    int i = blockIdx.x * blockDim.x + threadIdx.x;
    if (i < NN) atomicAdd(&h[batch[i]], 1);
    __syncthreads();
    if (threadIdx.x < NG) {
        int v = h[threadIdx.x];
        if (v > 0) atomicAdd(&cnt[threadIdx.x], (float)v);
    }
}

// ---------------- bucket histogram (dst>>8), LDS-staged ----------------
__global__ __launch_bounds__(256) void bucket_hist_kernel(const int* __restrict__ ei,
                                                          int* __restrict__ bhist) {
    __shared__ int h[NBK];
    for (int t = threadIdx.x; t < NBK; t += 256) h[t] = 0;
    __syncthreads();
    const int base = blockIdx.x * CHUNK;
    const int end = min(base + CHUNK, EE);
    for (int e = base + threadIdx.x; e < end; e += 256)
        atomicAdd(&h[ei[EE + e] >> 8], 1);
    __syncthreads();
    for (int t = threadIdx.x; t < NBK; t += 256)
        if (h[t]) atomicAdd(&bhist[t], h[t]);
}

// ---------------- serial scan of 391 bucket counts ----------------
__global__ void bucket_scan_kernel(const int* __restrict__ bhist,
                                   int* __restrict__ bbase, int* __restrict__ bcur) {
    if (threadIdx.x == 0) {
        int acc = 0;
        for (int i = 0; i < NBK; i++) {
            bbase[i] = acc; bcur[i] = acc; acc += bhist[i];
        }
        bbase[NBK] = acc;    // == EE
    }
}

// ---------------- scatter edges into bucket-major packed records ----------------
// record = (dst & 255) << 17 | src   (src < 2^17, dstlocal < 2^8)
__global__ __launch_bounds__(256) void bucket_scatter_kernel(const int* __restrict__ ei,
                                                             int* __restrict__ bcur,
                                                             unsigned* __restrict__ bmaj) {
    __shared__ int h[NBK];
    for (int t = threadIdx.x; t < NBK; t += 256) h[t] = 0;
    __syncthreads();
    const int base = blockIdx.x * CHUNK;
    const int end = min(base + CHUNK, EE);
    for (int e = base + threadIdx.x; e < end; e += 256)
        atomicAdd(&h[ei[EE + e] >> 8], 1);
    __syncthreads();
    // block-level reservation: one global atomic per touched bucket
    for (int t = threadIdx.x; t < NBK; t += 256) {
        int c = h[t];
        h[t] = c ? atomicAdd(&bcur[t], c) : 0;
    }
    __syncthreads();
    for (int e = base + threadIdx.x; e < end; e += 256) {
        int d = ei[EE + e];
        int s = ei[e];
        int b = d >> 8;
        int p = atomicAdd(&h[b], 1);
        bmaj[p] = (unsigned)s | ((unsigned)(d & 255) << 17);
    }
}

// ---------------- per-bucket: degree, rowend, dinv, dense csrcol ----------------
__global__ __launch_bounds__(256) void bucket_csr_kernel(const unsigned* __restrict__ bmaj,
                                                         const int* __restrict__ bbase,
                                                         int* __restrict__ rowend,
                                                         float* __restrict__ dinv,
                                                         int* __restrict__ csrcol) {
    __shared__ int h[256];
    __shared__ int sc[256];
    __shared__ int cur[256];
    const int b = blockIdx.x;
    const int t = threadIdx.x;
    const int e0 = bbase[b], e1 = bbase[b + 1];
    h[t] = 0;
    __syncthreads();
    for (int e = e0 + t; e < e1; e += 256)
        atomicAdd(&h[bmaj[e] >> 17], 1);
    __syncthreads();
    int deg = h[t];
    sc[t] = deg;
    __syncthreads();
    for (int off = 1; off < 256; off <<= 1) {
        int tmp = (t >= off) ? sc[t - off] : 0;
        __syncthreads();
        sc[t] += tmp;
        __syncthreads();
    }
    int incl = sc[t];
    int node = b * 256 + t;
    if (node < NN) {
        rowend[node] = e0 + incl;
        dinv[node] = rsqrtf((float)deg + 1.0f);
    }
    cur[t] = e0 + incl - deg;
    __syncthreads();
    for (int e = e0 + t; e < e1; e += 256) {
        unsigned v = bmaj[e];
        int p = atomicAdd(&cur[v >> 17], 1);
        csrcol[p] = (int)(v & 0x1FFFFu);
    }
}

// ---------------- W1 -> bf16 fragment-order pack ----------------
__global__ __launch_bounds__(256) void w1pack_kernel(const float* __restrict__ W1,
                                                     ushort* __restrict__ w1f) {
    int t = blockIdx.x * 256 + threadIdx.x;   // 0..65535 = k*256 + n
    int k = t >> 8, n = t & 255;
    int kb = k >> 5, q = (k >> 3) & 3, j = k & 7;
    int nt = n >> 4, ln = (n & 15) + q * 16;
    w1f[(size_t)(((kb * 16 + nt) * 64) + ln) * 8 + j] = f2bf(W1[t]);
}

// ---------------- g = fp8((x @ W1) * dinv[row]) — MFMA, LDS-free ----------------
__global__ __launch_bounds__(256) void gemm_mfma_kernel(const float* __restrict__ x,
                                                        const ushort* __restrict__ w1f,
                                                        const float* __restrict__ dinv,
                                                        uchar* __restrict__ g) {
    const int lane = threadIdx.x & 63;
    const int wid = threadIdx.x >> 6;
    const int wave = blockIdx.x * 4 + wid;
    const int r0 = wave * 32;
    if (r0 >= NN) return;
    const int mrow = lane & 15;
    const int q = lane >> 4;

    f32x4 acc[2][16];
    #pragma unroll
    for (int mt = 0; mt < 2; mt++)
        #pragma unroll
        for (int nt = 0; nt < 16; nt++)
            acc[mt][nt] = (f32x4){0.f, 0.f, 0.f, 0.f};

    const float* xp0 = x + (size_t)(r0 + mrow) * C + q * 8;
    const float* xp1 = xp0 + (size_t)16 * C;
    const ushort* bp = w1f + (size_t)lane * 8;

    #pragma unroll 1
    for (int kb = 0; kb < 8; kb++) {
        const int ko = kb * 32;
        float4 a0lo = *(const float4*)(xp0 + ko);
        float4 a0hi = *(const float4*)(xp0 + ko + 4);
        float4 a1lo = *(const float4*)(xp1 + ko);
        float4 a1hi = *(const float4*)(xp1 + ko + 4);
        bf16x8 a0, a1;
        a0[0] = (__bf16)a0lo.x; a0[1] = (__bf16)a0lo.y;
        a0[2] = (__bf16)a0lo.z; a0[3] = (__bf16)a0lo.w;
        a0[4] = (__bf16)a0hi.x; a0[5] = (__bf16)a0hi.y;
        a0[6] = (__bf16)a0hi.z; a0[7] = (__bf16)a0hi.w;
        a1[0] = (__bf16)a1lo.x; a1[1] = (__bf16)a1lo.y;
        a1[2] = (__bf16)a1lo.z; a1[3] = (__bf16)a1lo.w;
        a1[4] = (__bf16)a1hi.x; a1[5] = (__bf16)a1hi.y;
        a1[6] = (__bf16)a1hi.z; a1[7] = (__bf16)a1hi.w;

        const ushort* bkb = bp + (size_t)kb * 16 * 512;
        #pragma unroll
        for (int nt = 0; nt < 16; nt++) {
            bf16x8 bb = as_bf16x8(*(const uint4*)(bkb + (size_t)nt * 512));
            acc[0][nt] = __builtin_amdgcn_mfma_f32_16x16x32_bf16(a0, bb, acc[0][nt], 0, 0, 0);
            acc[1][nt] = __builtin_amdgcn_mfma_f32_16x16x32_bf16(a1, bb, acc[1][nt], 0, 0, 0);
        }
    }

    #pragma unroll
    for (int mt = 0; mt < 2; mt++) {
        #pragma unroll
        for (int r = 0; r < 4; r++) {
            int row = r0 + mt * 16 + q * 4 + r;
            float dv = dinv[row];
            uchar* gp = g + (size_t)row * C + mrow;
            #pragma unroll
            for (int nt = 0; nt < 16; nt++)
                gp[nt * 16] = f2fp8(acc[mt][nt][r] * dv);
        }
    }
}

// ---------------- aggregate + relu + fused mean-pool (fp8 gather, unroll 8) ----------------
__global__ __launch_bounds__(256) void agg_pool_kernel(const unsigned* __restrict__ g32,
                                                       const int* __restrict__ rowend,
                                                       const int* __restrict__ csrcol,
                                                       const float* __restrict__ dinv,
                                                       const float* __restrict__ b1,
                                                       const int* __restrict__ batch,
                                                       float* __restrict__ sums) {
    const int lane = threadIdx.x & 63;
    const int wid = threadIdx.x >> 6;
    const int c4 = lane * 4;
    const int nodeA = blockIdx.x * NODES_PER_BLOCK + wid * NODES_PER_GROUP;
    const float4 bv = *(const float4*)&b1[c4];

    float4 pool = make_float4(0.f, 0.f, 0.f, 0.f);
    int curb = -1;
    int rprev = (nodeA == 0) ? 0 : rowend[nodeA - 1];

    #pragma unroll 1
    for (int i = nodeA; i < nodeA + NODES_PER_GROUP; i++) {
        int r1 = rowend[i];
        int r0 = rprev;
        rprev = r1;
        int bi = batch[i];
        if (bi != curb) {
            if (curb >= 0) {
                atomicAdd(&sums[curb * C + c4 + 0], pool.x);
                atomicAdd(&sums[curb * C + c4 + 1], pool.y);
                atomicAdd(&sums[curb * C + c4 + 2], pool.z);
                atomicAdd(&sums[curb * C + c4 + 3], pool.w);
            }
            curb = bi;
            pool = make_float4(0.f, 0.f, 0.f, 0.f);
        }
        float4 s = make_float4(0.f, 0.f, 0.f, 0.f);
        acc_fp8x4(s, g32[(size_t)i * 64 + lane]);     // self-loop term
        int e = r0;
        for (; e + 8 <= r1; e += 8) {
            int i0 = csrcol[e],     i1 = csrcol[e + 1];
            int i2 = csrcol[e + 2], i3 = csrcol[e + 3];
            int i4 = csrcol[e + 4], i5 = csrcol[e + 5];
            int i6 = csrcol[e + 6], i7 = csrcol[e + 7];
            unsigned v0 = g32[(size_t)i0 * 64 + lane];
            unsigned v1 = g32[(size_t)i1 * 64 + lane];
            unsigned v2 = g32[(size_t)i2 * 64 + lane];
            unsigned v3 = g32[(size_t)i3 * 64 + lane];
            unsigned v4 = g32[(size_t)i4 * 64 + lane];
            unsigned v5 = g32[(size_t)i5 * 64 + lane];
            unsigned v6 = g32[(size_t)i6 * 64 + lane];
            unsigned v7 = g32[(size_t)i7 * 64 + lane];
            acc_fp8x4(s, v0); acc_fp8x4(s, v1); acc_fp8x4(s, v2); acc_fp8x4(s, v3);
            acc_fp8x4(s, v4); acc_fp8x4(s, v5); acc_fp8x4(s, v6); acc_fp8x4(s, v7);
        }
        for (; e < r1; e++)
            acc_fp8x4(s, g32[(size_t)csrcol[e] * 64 + lane]);

        float dv = dinv[i];
        pool.x += fmaxf(fmaf(dv, s.x, bv.x), 0.f);
        pool.y += fmaxf(fmaf(dv, s.y, bv.y), 0.f);
        pool.z += fmaxf(fmaf(dv, s.z, bv.z), 0.f);
        pool.w += fmaxf(fmaf(dv, s.w, bv.w), 0.f);
    }
    if (curb >= 0) {
        atomicAdd(&sums[curb * C + c4 + 0], pool.x);
        atomicAdd(&sums[curb * C + c4 + 1], pool.y);
        atomicAdd(&sums[curb * C + c4 + 2], pool.z);
        atomicAdd(&sums[curb * C + c4 + 3], pool.w);
    }
}

// ---------------- pooled = sums/cnt; out = pooled @ W2 + b2 ----------------
__global__ __launch_bounds__(256) void final_kernel(const float* __restrict__ sums,
                                                    const float* __restrict__ cnt,
                                                    const float* __restrict__ W2,
                                                    const float* __restrict__ b2,
                                                    float* __restrict__ out) {
    __shared__ float p[C];
    int gi = blockIdx.x;
    float cdiv = fmaxf(cnt[gi], 1.0f);
    p[threadIdx.x] = sums[gi * C + threadIdx.x] / cdiv;
    __syncthreads();
    if (threadIdx.x < OUTC) {
        float acc = b2[threadIdx.x];
        for (int k = 0; k < C; k++) acc += p[k] * W2[k * OUTC + threadIdx.x];
        out[gi * OUTC + threadIdx.x] = acc;
    }
}

extern "C" void kernel_launch(void* const* d_in, const int* in_sizes, int n_in,
                              void* d_out, int out_size, void* d_ws, size_t ws_size,
                              hipStream_t stream) {
    const float* x     = (const float*)d_in[0];
    const int*   ei    = (const int*)d_in[1];
    const int*   batch = (const int*)d_in[2];
    const float* W1    = (const float*)d_in[3];
    const float* b1    = (const float*)d_in[4];
    const float* W2    = (const float*)d_in[5];
    const float* b2    = (const float*)d_in[6];
    float* out = (float*)d_out;

    char* w = (char*)d_ws;
    size_t off = 0;
    auto carve = [&](size_t bytes) {
        void* p = w + off;
        off = (off + bytes + 255) & ~(size_t)255;
        return p;
    };
    uchar*    g        = (uchar*)   carve((size_t)NN * C);        // fp8 e4m3
    int*      rowend   = (int*)     carve((size_t)NN * 4);
    float*    dinv     = (float*)   carve((size_t)NN * 4);
    int*      csrcol   = (int*)     carve((size_t)EE * 4);
    unsigned* bmaj     = (unsigned*)carve((size_t)EE * 4);
    int*      bbase    = (int*)     carve((size_t)(NBK + 1) * 4);
    int*      bcur     = (int*)     carve((size_t)NBK * 4);
    ushort*   w1f      = (ushort*)  carve((size_t)C * C * 2);
    // contiguous zero-init region:
    int*      bhist    = (int*)     carve((size_t)NBK * 4);
    float*    sums     = (float*)   carve((size_t)NG * C * 4);
    float*    cnt      = (float*)   carve((size_t)NG * 4);
    size_t zero_bytes = (size_t)((char*)cnt + (size_t)NG * 4 - (char*)bhist);

    hipMemsetAsync(bhist, 0, zero_bytes, stream);

    bucket_hist_kernel<<<NBLK1, 256, 0, stream>>>(ei, bhist);
    bucket_scan_kernel<<<1, 64, 0, stream>>>(bhist, bbase, bcur);
    bucket_scatter_kernel<<<NBLK1, 256, 0, stream>>>(ei, bcur, bmaj);
    bucket_csr_kernel<<<NBK, 256, 0, stream>>>(bmaj, bbase, rowend, dinv, csrcol);
    count_kernel<<<(NN + 1023) / 1024, 1024, 0, stream>>>(batch, cnt);
    w1pack_kernel<<<C * C / 256, 256, 0, stream>>>(W1, w1f);
    gemm_mfma_kernel<<<(NN / 32 + 3) / 4, 256, 0, stream>>>(x, w1f, dinv, g);
    agg_pool_kernel<<<NN / NODES_PER_BLOCK, 256, 0, stream>>>(
        (const unsigned*)g, rowend, csrcol, dinv, b1, batch, sums);
    final_kernel<<<NG, 256, 0, stream>>>(sums, cnt, W2, b2, out);
}